// Round 1
// baseline (1039.878 us; speedup 1.0000x reference)
//
#include <hip/hip_runtime.h>
#include <math.h>

#define NQ 100
#define MM 400
#define DD 512
#define KK 10

// ---- workspace byte offsets ----
// Xs    : 100*400*512 f32 = 81,920,000
// idx16 : 40000*16 int    =  2,560,000   @ 81,920,000
// valsd : 40000*10 f64    =  3,200,000   @ 84,480,000
// idx10 : 40000*10 int    =  1,600,000   @ 87,680,000
// resd  : 40000 f64       =    320,000   @ 89,280,000
// total 89,600,000 bytes
#define OFF_IDX16 81920000UL
#define OFF_VALSD 84480000UL
#define OFF_IDX10 87680000UL
#define OFF_RESD  89280000UL

// ---------------------------------------------------------------------------
// K1: gather Xs[q][m][:] = X[ranks[m][q]][:]   (ranks is [N_db][NQ] row-major)
// ---------------------------------------------------------------------------
__global__ void k_gather(const float* __restrict__ X, const int* __restrict__ ranks,
                         float* __restrict__ Xs) {
  int gid = blockIdx.x * 256 + threadIdx.x;        // 100*400*128 = 5,120,000 exactly
  int c4  = gid & 127;
  int row = gid >> 7;                              // q*MM + m
  int q   = row / MM;
  int m   = row - q * MM;
  int id  = ranks[m * NQ + q];
  float4 v = ((const float4*)X)[(size_t)id * 128 + c4];
  ((float4*)Xs)[(size_t)row * 128 + c4] = v;
}

// ---------------------------------------------------------------------------
// K2: f32 screening GEMM  S = Xs Xs^T  (per query), fused top-16 per row.
// Tile: 32 rows x 128 cols, 4x4 micro-tile, 256 threads, n-loop inside block.
// LDS: As[16][32] + Bs[16][128] + Cs[32][408] = 62.2 KB  -> 2 blocks/CU
// ---------------------------------------------------------------------------
#define TM 32
#define TN 128
#define KC 16

__launch_bounds__(256, 2)
__global__ void k_score_top16(const float* __restrict__ Xs, int* __restrict__ idx16) {
  __shared__ float As[KC][TM];     // [k][m] transposed for b128 reads
  __shared__ float Bs[KC][TN];     // [k][n]
  __shared__ float Cs[TM][408];    // full 400-col row slice (+pad)

  const int q   = blockIdx.y;
  const int m0  = blockIdx.x * TM;        // 13 m-tiles -> up to 416 (tail masked)
  const int tid = threadIdx.x;
  const int tr  = tid & 7;                // row group 0..7  (rows tr*4..tr*4+3)
  const int tc  = tid >> 3;               // col group 0..31 (cols tc*4..tc*4+3)
  const float* Xq = Xs + (size_t)q * MM * DD;

  for (int nt = 0; nt < 4; ++nt) {
    const int n0 = nt * TN;
    float acc[4][4] = {{0.f,0.f,0.f,0.f},{0.f,0.f,0.f,0.f},
                       {0.f,0.f,0.f,0.f},{0.f,0.f,0.f,0.f}};
    for (int kc = 0; kc < DD; kc += KC) {
      __syncthreads();   // protect As/Bs from previous iteration's readers
      // stage A: 32 rows x 16 k -> transposed. 2 floats/thread.
      {
        int r  = tid >> 3;               // 0..31
        int cc = (tid & 7) * 2;          // 0..14
        int mrow = m0 + r; if (mrow > MM - 1) mrow = MM - 1;   // clamp (tail rows discarded)
        float2 a = *(const float2*)(Xq + (size_t)mrow * DD + kc + cc);
        As[cc + 0][r] = a.x;
        As[cc + 1][r] = a.y;
      }
      // stage B: 128 rows x 16 k -> transposed. 8 floats/thread.
      {
        int r  = tid >> 1;               // 0..127
        int cc = (tid & 1) * 8;          // 0 or 8
        int nrow = n0 + r; if (nrow > MM - 1) nrow = MM - 1;   // clamp (cols>=400 masked)
        const float* src = Xq + (size_t)nrow * DD + kc + cc;
        #pragma unroll
        for (int j = 0; j < 2; ++j) {
          float4 b = *(const float4*)(src + 4 * j);
          Bs[cc + 4*j + 0][r] = b.x;
          Bs[cc + 4*j + 1][r] = b.y;
          Bs[cc + 4*j + 2][r] = b.z;
          Bs[cc + 4*j + 3][r] = b.w;
        }
      }
      __syncthreads();
      #pragma unroll
      for (int k = 0; k < KC; ++k) {
        float4 a4 = *(const float4*)&As[k][tr * 4];
        float4 b4 = *(const float4*)&Bs[k][tc * 4];
        float av[4] = {a4.x, a4.y, a4.z, a4.w};
        float bw[4] = {b4.x, b4.y, b4.z, b4.w};
        #pragma unroll
        for (int i = 0; i < 4; ++i)
          #pragma unroll
          for (int j = 0; j < 4; ++j)
            acc[i][j] = fmaf(av[i], bw[j], acc[i][j]);
      }
    }
    // spill this n-slice to Cs (guard col<400; Cs has 408 cols)
    #pragma unroll
    for (int i = 0; i < 4; ++i) {
      int r = tr * 4 + i;
      #pragma unroll
      for (int j = 0; j < 4; ++j) {
        int col = n0 + tc * 4 + j;
        if (col < MM) Cs[r][col] = acc[i][j];
      }
    }
  }
  __syncthreads();

  // top-16 per row (f32 screen; exact top-10 refined later in f64).
  const int lane = tid & 63;
  const int wv   = tid >> 6;
  for (int r = wv; r < TM; r += 4) {
    const int m = m0 + r;
    if (m >= MM) continue;               // wave-uniform
    float v[7]; int nn[7];
    #pragma unroll
    for (int s = 0; s < 7; ++s) {
      int n = lane + 64 * s;
      bool ok = (n < MM);
      v[s]  = ok ? Cs[r][n] : -INFINITY;
      nn[s] = ok ? n : 0x7fffffff;
    }
    for (int t = 0; t < 16; ++t) {
      float bv = v[0]; int bn = nn[0];
      #pragma unroll
      for (int s = 1; s < 7; ++s)
        if (v[s] > bv || (v[s] == bv && nn[s] < bn)) { bv = v[s]; bn = nn[s]; }
      for (int off = 32; off; off >>= 1) {
        float ov = __shfl_xor(bv, off);
        int   on = __shfl_xor(bn, off);
        if (ov > bv || (ov == bv && on < bn)) { bv = ov; bn = on; }
      }
      if (lane == 0) idx16[((size_t)q * MM + m) * 16 + t] = bn;
      #pragma unroll
      for (int s = 0; s < 7; ++s)
        if (nn[s] == bn) v[s] = -INFINITY;
    }
  }
}

// ---------------------------------------------------------------------------
// K2b: refine the 16 screened candidates in f64 (exact products of f32),
// pick exact top-10 with index tie-break (matches lax.top_k semantics).
// One wave per (q,m) row.
// ---------------------------------------------------------------------------
__global__ void k_refine(const float* __restrict__ Xs, const int* __restrict__ idx16,
                         double* __restrict__ valsd, int* __restrict__ idx10) {
  const int row  = blockIdx.x;           // q*MM + m
  const int q    = row / MM;
  const int m    = row - q * MM;
  const int lane = threadIdx.x;          // 64
  const float* Xq = Xs + (size_t)q * MM * DD;

  double a[8];
  {
    const float* ar = Xq + (size_t)m * DD + lane * 8;
    float4 a0 = *(const float4*)(ar);
    float4 a1 = *(const float4*)(ar + 4);
    a[0]=a0.x; a[1]=a0.y; a[2]=a0.z; a[3]=a0.w;
    a[4]=a1.x; a[5]=a1.y; a[6]=a1.z; a[7]=a1.w;
  }
  __shared__ double sv[16];
  __shared__ int    si[16];
  for (int j = 0; j < 16; ++j) {
    int n = idx16[(size_t)row * 16 + j];
    const float* br = Xq + (size_t)n * DD + lane * 8;
    float4 b0 = *(const float4*)(br);
    float4 b1 = *(const float4*)(br + 4);
    double s = a[0]*(double)b0.x + a[1]*(double)b0.y + a[2]*(double)b0.z + a[3]*(double)b0.w
             + a[4]*(double)b1.x + a[5]*(double)b1.y + a[6]*(double)b1.z + a[7]*(double)b1.w;
    for (int off = 32; off; off >>= 1) s += __shfl_xor(s, off);
    if (lane == 0) { sv[j] = s; si[j] = n; }
  }
  __syncthreads();
  if (lane < 16) {
    double v = sv[lane]; int n = si[lane];
    int rank = 0;
    for (int i = 0; i < 16; ++i)
      if (sv[i] > v || (sv[i] == v && si[i] < n)) ++rank;
    if (rank < KK) {
      valsd[(size_t)row * KK + rank] = v;
      idx10[(size_t)row * KK + rank] = n;
    }
  }
}

// ---------------------------------------------------------------------------
// K3: x_dba (f64 accumulate, f32 out) + res_top (f64, kept for argsort).
// One block (128 threads) per (q,m); thread owns 4 consecutive channels.
// ---------------------------------------------------------------------------
__global__ void k_dba(const float* __restrict__ Xs, const float* __restrict__ Q,
                      const double* __restrict__ valsd, const int* __restrict__ idx10,
                      float* __restrict__ out_x, float* __restrict__ out_rt,
                      double* __restrict__ resd) {
  const int row = blockIdx.x;            // q*MM + m
  const int q   = row / MM;
  const int tid = threadIdx.x;           // 128
  const float* Xq = Xs + (size_t)q * MM * DD;

  double w[KK]; int id[KK]; double denom = 0.0;
  #pragma unroll
  for (int k = 0; k < KK; ++k) {
    double vv = valsd[(size_t)row * KK + k];
    w[k] = (k == 0) ? 1.0 : 0.15 * vv;
    denom += w[k];
    id[k] = idx10[(size_t)row * KK + k];
  }
  double acc0 = 0, acc1 = 0, acc2 = 0, acc3 = 0;
  #pragma unroll
  for (int k = 0; k < KK; ++k) {
    float4 g = *(const float4*)(Xq + (size_t)id[k] * DD + tid * 4);
    acc0 += w[k] * (double)g.x;
    acc1 += w[k] * (double)g.y;
    acc2 += w[k] * (double)g.z;
    acc3 += w[k] * (double)g.w;
  }
  double x0 = acc0 / denom, x1 = acc1 / denom, x2 = acc2 / denom, x3 = acc3 / denom;
  float4 xo = make_float4((float)x0, (float)x1, (float)x2, (float)x3);
  ((float4*)out_x)[(size_t)row * 128 + tid] = xo;

  const float* Qr = Q + (size_t)q * DD + tid * 4;
  double p = x0 * (double)Qr[0] + x1 * (double)Qr[1] + x2 * (double)Qr[2] + x3 * (double)Qr[3];
  for (int off = 32; off; off >>= 1) p += __shfl_xor(p, off);
  __shared__ double ps[2];
  if ((tid & 63) == 0) ps[tid >> 6] = p;
  __syncthreads();
  if (tid == 0) {
    double rt = ps[0] + ps[1];
    resd[row]   = rt;
    out_rt[row] = (float)rt;
  }
}

// ---------------------------------------------------------------------------
// K4: stable descending argsort of res_top (f64) per query via rank-count,
// then pre + rerank_final (written as f32; ids < 2^24 are exact).
// ---------------------------------------------------------------------------
__global__ void k_sort(const double* __restrict__ resd, const int* __restrict__ ranks,
                       float* __restrict__ out_rr, float* __restrict__ out_pre) {
  const int q   = blockIdx.x;
  const int tid = threadIdx.x;           // 512
  __shared__ double sv[MM];
  if (tid < MM) sv[tid] = resd[(size_t)q * MM + tid];
  __syncthreads();
  if (tid < MM) {
    double v = sv[tid];
    int rank = 0;
    for (int j = 0; j < MM; ++j) {
      double u = sv[j];
      rank += (u > v) || (u == v && j < tid);
    }
    out_pre[(size_t)q * MM + rank] = (float)tid;
    out_rr [(size_t)q * MM + rank] = (float)ranks[tid * NQ + q];
  }
}

// ---------------------------------------------------------------------------
extern "C" void kernel_launch(void* const* d_in, const int* in_sizes, int n_in,
                              void* d_out, int out_size, void* d_ws, size_t ws_size,
                              hipStream_t stream) {
  const float* X     = (const float*)d_in[0];
  const float* Q     = (const float*)d_in[1];
  const int*   ranks = (const int*)d_in[2];

  float*  out    = (float*)d_out;
  float*  out_rr = out;                   // rerank_final [100][400]
  float*  out_rt = out + 40000;           // res_top      [100][400]
  float*  out_pr = out + 80000;           // pre          [100][400]
  float*  out_x  = out + 120000;          // x_dba        [100][400][512]

  float*  Xs    = (float*)d_ws;
  int*    idx16 = (int*)   ((char*)d_ws + OFF_IDX16);
  double* valsd = (double*)((char*)d_ws + OFF_VALSD);
  int*    idx10 = (int*)   ((char*)d_ws + OFF_IDX10);
  double* resd  = (double*)((char*)d_ws + OFF_RESD);

  k_gather     <<<dim3(20000),   dim3(256), 0, stream>>>(X, ranks, Xs);
  k_score_top16<<<dim3(13, 100), dim3(256), 0, stream>>>(Xs, idx16);
  k_refine     <<<dim3(40000),   dim3(64),  0, stream>>>(Xs, idx16, valsd, idx10);
  k_dba        <<<dim3(40000),   dim3(128), 0, stream>>>(Xs, Q, valsd, idx10, out_x, out_rt, resd);
  k_sort       <<<dim3(100),     dim3(512), 0, stream>>>(resd, ranks, out_rr, out_pr);
}

// Round 2
// 603.317 us; speedup vs baseline: 1.7236x; 1.7236x over previous
//
#include <hip/hip_runtime.h>
#include <math.h>

#define NQ 100
#define MM 400
#define DD 512
#define KK 10
#define NS 20           // screened candidates per row (true top-10 must be subset)

typedef short v8s __attribute__((ext_vector_type(8)));   // 8 bf16 (4 VGPRs)
typedef float v4f __attribute__((ext_vector_type(4)));   // 4 f32 acc

// ---- NEW-path workspace byte offsets ----
// Xs f32 : 100*400*512*4 = 81,920,000  @ 0
// S  f32 : 100*400*400*4 = 64,000,000  @  81,920,000
// Xs bf16: 100*400*512*2 = 40,960,000  @ 145,920,000
// idx20  : 40000*20*4    =  3,200,000  @ 186,880,000
// valsd  : 40000*10*8    =  3,200,000  @ 190,080,000
// idx10  : 40000*10*4    =  1,600,000  @ 193,280,000
// resd   : 40000*8       =    320,000  @ 194,880,000
#define NOFF_S     81920000UL
#define NOFF_XB   145920000UL
#define NOFF_IDX  186880000UL
#define NOFF_VALS 190080000UL
#define NOFF_I10  193280000UL
#define NOFF_RES  194880000UL
#define NEED_NEW  195200000UL

// ---- OLD-path (fallback) offsets, as round 1 ----
#define OOFF_IDX16 81920000UL
#define OOFF_VALSD 84480000UL
#define OOFF_IDX10 87680000UL
#define OOFF_RESD  89280000UL

static __device__ __forceinline__ unsigned short f2bf(float x) {
  unsigned u = __float_as_uint(x);
  unsigned r = (u + 0x7FFFu + ((u >> 16) & 1u)) >> 16;   // RNE; inputs have no NaN
  return (unsigned short)r;
}

// ---------------------------------------------------------------------------
// K1: gather Xs[q][m][:] = X[ranks[m][q]][:]  (f32) + bf16 copy for MFMA screen
// ---------------------------------------------------------------------------
__global__ void k_gather(const float* __restrict__ X, const int* __restrict__ ranks,
                         float* __restrict__ Xs, unsigned short* __restrict__ Xsb,
                         int make_bf) {
  int gid = blockIdx.x * 256 + threadIdx.x;        // 5,120,000 threads exactly
  int c4  = gid & 127;
  int row = gid >> 7;                              // q*MM + m
  int q   = row / MM;
  int m   = row - q * MM;
  int id  = ranks[m * NQ + q];
  float4 v = ((const float4*)X)[(size_t)id * 128 + c4];
  ((float4*)Xs)[(size_t)row * 128 + c4] = v;
  if (make_bf) {
    ushort4 h;
    h.x = f2bf(v.x); h.y = f2bf(v.y); h.z = f2bf(v.z); h.w = f2bf(v.w);
    ((ushort4*)Xsb)[(size_t)row * 128 + c4] = h;
  }
}

// ---------------------------------------------------------------------------
// K2 (new): bf16 MFMA screening GEMM  S = Xs Xs^T per query, S materialized f32.
// Block 256 thr = 4 waves; block tile 128x128; wave tile 64x64 (4x4 frags of
// 16x16x32). LDS: As/Bs 128 x 32 bf16, row stride 40 (+8 pad breaks conflicts).
// ---------------------------------------------------------------------------
#define LDB 40
__launch_bounds__(256)
__global__ void k_gemm(const unsigned short* __restrict__ Xsb, float* __restrict__ S) {
  __shared__ unsigned short As[128 * LDB];
  __shared__ unsigned short Bs[128 * LDB];

  const int q    = blockIdx.y;
  const int mt   = blockIdx.x >> 2;
  const int nt   = blockIdx.x & 3;
  const int m0   = mt * 128, n0 = nt * 128;
  const int tid  = threadIdx.x;
  const int wave = tid >> 6, lane = tid & 63;
  const int wr   = wave >> 1, wc = wave & 1;       // wave origin in block tile
  const int frow = lane & 15, quad = lane >> 4;

  const unsigned short* Xq = Xsb + (size_t)q * MM * DD;

  v4f acc[4][4];
  #pragma unroll
  for (int i = 0; i < 4; ++i)
    #pragma unroll
    for (int j = 0; j < 4; ++j)
      acc[i][j] = (v4f){0.f, 0.f, 0.f, 0.f};

  const int sr = tid >> 1;                 // staging row 0..127
  const int sk = (tid & 1) * 16;           // staging k-half

  for (int kc = 0; kc < DD; kc += 32) {
    __syncthreads();
    {  // stage A rows (m-block)
      int mrow = m0 + sr; if (mrow > MM - 1) mrow = MM - 1;
      const unsigned short* src = Xq + (size_t)mrow * DD + kc + sk;
      v8s t0 = *(const v8s*)(src);
      v8s t1 = *(const v8s*)(src + 8);
      *(v8s*)&As[sr * LDB + sk]     = t0;
      *(v8s*)&As[sr * LDB + sk + 8] = t1;
    }
    {  // stage B rows (n-block)
      int nrow = n0 + sr; if (nrow > MM - 1) nrow = MM - 1;
      const unsigned short* src = Xq + (size_t)nrow * DD + kc + sk;
      v8s t0 = *(const v8s*)(src);
      v8s t1 = *(const v8s*)(src + 8);
      *(v8s*)&Bs[sr * LDB + sk]     = t0;
      *(v8s*)&Bs[sr * LDB + sk + 8] = t1;
    }
    __syncthreads();

    v8s a[4], b[4];
    #pragma unroll
    for (int i = 0; i < 4; ++i)
      a[i] = *(const v8s*)&As[(wr * 64 + i * 16 + frow) * LDB + quad * 8];
    #pragma unroll
    for (int j = 0; j < 4; ++j)
      b[j] = *(const v8s*)&Bs[(wc * 64 + j * 16 + frow) * LDB + quad * 8];
    #pragma unroll
    for (int i = 0; i < 4; ++i)
      #pragma unroll
      for (int j = 0; j < 4; ++j)
        acc[i][j] = __builtin_amdgcn_mfma_f32_16x16x32_bf16(a[i], b[j], acc[i][j], 0, 0, 0);
  }

  // epilogue: C layout col=lane&15, row=quad*4+reg  [m89-verified]
  #pragma unroll
  for (int j = 0; j < 4; ++j) {
    int n = n0 + wc * 64 + j * 16 + frow;
    if (n >= MM) continue;
    #pragma unroll
    for (int i = 0; i < 4; ++i) {
      #pragma unroll
      for (int r = 0; r < 4; ++r) {
        int m = m0 + wr * 64 + i * 16 + quad * 4 + r;
        if (m < MM) S[((size_t)q * MM + m) * MM + n] = acc[i][j][r];
      }
    }
  }
}

// ---------------------------------------------------------------------------
// K2b (new): per-row top-NS screen over S. One wave per row; packed u64 key
// (monotone f32 bits || ~idx) so value-desc + idx-asc tie-break is a single max.
// ---------------------------------------------------------------------------
__global__ void k_topk(const float* __restrict__ S, int* __restrict__ idxNS) {
  const int row  = blockIdx.x * 4 + (threadIdx.x >> 6);
  const int lane = threadIdx.x & 63;
  const float* Sr = S + (size_t)row * MM;

  unsigned long long key[7];
  #pragma unroll
  for (int s = 0; s < 7; ++s) {
    int n = lane + 64 * s;
    if (n < MM) {
      unsigned u = __float_as_uint(Sr[n]);
      u ^= (u >> 31) ? 0xFFFFFFFFu : 0x80000000u;          // monotone map
      key[s] = ((unsigned long long)u << 32) | (unsigned long long)(0xFFFFFFFFu - (unsigned)n);
    } else {
      key[s] = 0ull;
    }
  }
  for (int t = 0; t < NS; ++t) {
    unsigned long long w = key[0];
    #pragma unroll
    for (int s = 1; s < 7; ++s) w = (key[s] > w) ? key[s] : w;
    #pragma unroll
    for (int off = 32; off; off >>= 1) {
      unsigned long long o = __shfl_xor(w, off);
      w = (o > w) ? o : w;
    }
    if (lane == 0) {
      int n = (int)(0xFFFFFFFFu - (unsigned)(w & 0xFFFFFFFFull));
      idxNS[(size_t)row * NS + t] = n;
    }
    #pragma unroll
    for (int s = 0; s < 7; ++s)
      if (key[s] == w) key[s] = 0ull;
  }
}

// ---------------------------------------------------------------------------
// OLD K2 (fallback if ws too small): f32 tile GEMM + fused top-16 (round 1)
// ---------------------------------------------------------------------------
#define TM 32
#define TN 128
#define KC 16
__launch_bounds__(256, 2)
__global__ void k_score_top16(const float* __restrict__ Xs, int* __restrict__ idx16) {
  __shared__ float As_[KC][TM];
  __shared__ float Bs_[KC][TN];
  __shared__ float Cs_[TM][408];
  const int q   = blockIdx.y;
  const int m0  = blockIdx.x * TM;
  const int tid = threadIdx.x;
  const int tr  = tid & 7;
  const int tc  = tid >> 3;
  const float* Xq = Xs + (size_t)q * MM * DD;
  for (int nt = 0; nt < 4; ++nt) {
    const int n0 = nt * TN;
    float acc[4][4] = {{0.f,0.f,0.f,0.f},{0.f,0.f,0.f,0.f},
                       {0.f,0.f,0.f,0.f},{0.f,0.f,0.f,0.f}};
    for (int kc = 0; kc < DD; kc += KC) {
      __syncthreads();
      { int r = tid >> 3; int cc = (tid & 7) * 2;
        int mrow = m0 + r; if (mrow > MM - 1) mrow = MM - 1;
        float2 a = *(const float2*)(Xq + (size_t)mrow * DD + kc + cc);
        As_[cc + 0][r] = a.x; As_[cc + 1][r] = a.y; }
      { int r = tid >> 1; int cc = (tid & 1) * 8;
        int nrow = n0 + r; if (nrow > MM - 1) nrow = MM - 1;
        const float* src = Xq + (size_t)nrow * DD + kc + cc;
        #pragma unroll
        for (int j = 0; j < 2; ++j) {
          float4 b = *(const float4*)(src + 4 * j);
          Bs_[cc + 4*j + 0][r] = b.x; Bs_[cc + 4*j + 1][r] = b.y;
          Bs_[cc + 4*j + 2][r] = b.z; Bs_[cc + 4*j + 3][r] = b.w; } }
      __syncthreads();
      #pragma unroll
      for (int k = 0; k < KC; ++k) {
        float4 a4 = *(const float4*)&As_[k][tr * 4];
        float4 b4 = *(const float4*)&Bs_[k][tc * 4];
        float av[4] = {a4.x, a4.y, a4.z, a4.w};
        float bw[4] = {b4.x, b4.y, b4.z, b4.w};
        #pragma unroll
        for (int i = 0; i < 4; ++i)
          #pragma unroll
          for (int j = 0; j < 4; ++j)
            acc[i][j] = fmaf(av[i], bw[j], acc[i][j]);
      }
    }
    #pragma unroll
    for (int i = 0; i < 4; ++i) {
      int r = tr * 4 + i;
      #pragma unroll
      for (int j = 0; j < 4; ++j) {
        int col = n0 + tc * 4 + j;
        if (col < MM) Cs_[r][col] = acc[i][j];
      }
    }
  }
  __syncthreads();
  const int lane = tid & 63;
  const int wv   = tid >> 6;
  for (int r = wv; r < TM; r += 4) {
    const int m = m0 + r;
    if (m >= MM) continue;
    float v[7]; int nn[7];
    #pragma unroll
    for (int s = 0; s < 7; ++s) {
      int n = lane + 64 * s;
      bool ok = (n < MM);
      v[s]  = ok ? Cs_[r][n] : -INFINITY;
      nn[s] = ok ? n : 0x7fffffff;
    }
    for (int t = 0; t < 16; ++t) {
      float bv = v[0]; int bn = nn[0];
      #pragma unroll
      for (int s = 1; s < 7; ++s)
        if (v[s] > bv || (v[s] == bv && nn[s] < bn)) { bv = v[s]; bn = nn[s]; }
      for (int off = 32; off; off >>= 1) {
        float ov = __shfl_xor(bv, off);
        int   on = __shfl_xor(bn, off);
        if (ov > bv || (ov == bv && on < bn)) { bv = ov; bn = on; }
      }
      if (lane == 0) idx16[((size_t)q * MM + m) * 16 + t] = bn;
      #pragma unroll
      for (int s = 0; s < 7; ++s)
        if (nn[s] == bn) v[s] = -INFINITY;
    }
  }
}

// ---------------------------------------------------------------------------
// K3: refine ns screened candidates in f64 (exact), emit exact top-10
// (value desc, index-asc ties — lax.top_k semantics). One wave per row.
// ---------------------------------------------------------------------------
__global__ void k_refine(const float* __restrict__ Xs, const int* __restrict__ idxbuf,
                         int ns, double* __restrict__ valsd, int* __restrict__ idx10) {
  const int row  = blockIdx.x;           // q*MM + m
  const int q    = row / MM;
  const int m    = row - q * MM;
  const int lane = threadIdx.x;          // 64
  const float* Xq = Xs + (size_t)q * MM * DD;

  double a[8];
  {
    const float* ar = Xq + (size_t)m * DD + lane * 8;
    float4 a0 = *(const float4*)(ar);
    float4 a1 = *(const float4*)(ar + 4);
    a[0]=a0.x; a[1]=a0.y; a[2]=a0.z; a[3]=a0.w;
    a[4]=a1.x; a[5]=a1.y; a[6]=a1.z; a[7]=a1.w;
  }
  __shared__ double sv[24];
  __shared__ int    si[24];
  for (int j = 0; j < ns; ++j) {
    int n = idxbuf[(size_t)row * ns + j];
    const float* br = Xq + (size_t)n * DD + lane * 8;
    float4 b0 = *(const float4*)(br);
    float4 b1 = *(const float4*)(br + 4);
    double s = a[0]*(double)b0.x + a[1]*(double)b0.y + a[2]*(double)b0.z + a[3]*(double)b0.w
             + a[4]*(double)b1.x + a[5]*(double)b1.y + a[6]*(double)b1.z + a[7]*(double)b1.w;
    for (int off = 32; off; off >>= 1) s += __shfl_xor(s, off);
    if (lane == 0) { sv[j] = s; si[j] = n; }
  }
  __syncthreads();
  if (lane < ns) {
    double v = sv[lane]; int n = si[lane];
    int rank = 0;
    for (int i = 0; i < ns; ++i)
      if (sv[i] > v || (sv[i] == v && si[i] < n)) ++rank;
    if (rank < KK) {
      valsd[(size_t)row * KK + rank] = v;
      idx10[(size_t)row * KK + rank] = n;
    }
  }
}

// ---------------------------------------------------------------------------
// K4: x_dba (f64 accumulate, f32 out) + res_top (f64 kept for argsort).
// ---------------------------------------------------------------------------
__global__ void k_dba(const float* __restrict__ Xs, const float* __restrict__ Q,
                      const double* __restrict__ valsd, const int* __restrict__ idx10,
                      float* __restrict__ out_x, float* __restrict__ out_rt,
                      double* __restrict__ resd) {
  const int row = blockIdx.x;            // q*MM + m
  const int q   = row / MM;
  const int tid = threadIdx.x;           // 128
  const float* Xq = Xs + (size_t)q * MM * DD;

  double w[KK]; int id[KK]; double denom = 0.0;
  #pragma unroll
  for (int k = 0; k < KK; ++k) {
    double vv = valsd[(size_t)row * KK + k];
    w[k] = (k == 0) ? 1.0 : 0.15 * vv;
    denom += w[k];
    id[k] = idx10[(size_t)row * KK + k];
  }
  double acc0 = 0, acc1 = 0, acc2 = 0, acc3 = 0;
  #pragma unroll
  for (int k = 0; k < KK; ++k) {
    float4 g = *(const float4*)(Xq + (size_t)id[k] * DD + tid * 4);
    acc0 += w[k] * (double)g.x;
    acc1 += w[k] * (double)g.y;
    acc2 += w[k] * (double)g.z;
    acc3 += w[k] * (double)g.w;
  }
  double x0 = acc0 / denom, x1 = acc1 / denom, x2 = acc2 / denom, x3 = acc3 / denom;
  ((float4*)out_x)[(size_t)row * 128 + tid] =
      make_float4((float)x0, (float)x1, (float)x2, (float)x3);

  const float* Qr = Q + (size_t)q * DD + tid * 4;
  double p = x0 * (double)Qr[0] + x1 * (double)Qr[1] + x2 * (double)Qr[2] + x3 * (double)Qr[3];
  for (int off = 32; off; off >>= 1) p += __shfl_xor(p, off);
  __shared__ double ps[2];
  if ((tid & 63) == 0) ps[tid >> 6] = p;
  __syncthreads();
  if (tid == 0) {
    double rt = ps[0] + ps[1];
    resd[row]   = rt;
    out_rt[row] = (float)rt;
  }
}

// ---------------------------------------------------------------------------
// K5: stable descending argsort of res_top (f64) per query → pre, rerank_final
// ---------------------------------------------------------------------------
__global__ void k_sort(const double* __restrict__ resd, const int* __restrict__ ranks,
                       float* __restrict__ out_rr, float* __restrict__ out_pre) {
  const int q   = blockIdx.x;
  const int tid = threadIdx.x;           // 512
  __shared__ double sv[MM];
  if (tid < MM) sv[tid] = resd[(size_t)q * MM + tid];
  __syncthreads();
  if (tid < MM) {
    double v = sv[tid];
    int rank = 0;
    for (int j = 0; j < MM; ++j) {
      double u = sv[j];
      rank += (u > v) || (u == v && j < tid);
    }
    out_pre[(size_t)q * MM + rank] = (float)tid;
    out_rr [(size_t)q * MM + rank] = (float)ranks[tid * NQ + q];
  }
}

// ---------------------------------------------------------------------------
extern "C" void kernel_launch(void* const* d_in, const int* in_sizes, int n_in,
                              void* d_out, int out_size, void* d_ws, size_t ws_size,
                              hipStream_t stream) {
  const float* X     = (const float*)d_in[0];
  const float* Q     = (const float*)d_in[1];
  const int*   ranks = (const int*)d_in[2];

  float* out    = (float*)d_out;
  float* out_rr = out;                   // rerank_final [100][400]
  float* out_rt = out + 40000;           // res_top      [100][400]
  float* out_pr = out + 80000;           // pre          [100][400]
  float* out_x  = out + 120000;          // x_dba        [100][400][512]

  float* Xs = (float*)d_ws;

  if (ws_size >= NEED_NEW) {
    float*          S     = (float*)          ((char*)d_ws + NOFF_S);
    unsigned short* Xsb   = (unsigned short*) ((char*)d_ws + NOFF_XB);
    int*            idxNS = (int*)            ((char*)d_ws + NOFF_IDX);
    double*         valsd = (double*)         ((char*)d_ws + NOFF_VALS);
    int*            idx10 = (int*)            ((char*)d_ws + NOFF_I10);
    double*         resd  = (double*)         ((char*)d_ws + NOFF_RES);

    k_gather<<<dim3(20000),   dim3(256), 0, stream>>>(X, ranks, Xs, Xsb, 1);
    k_gemm  <<<dim3(16, 100), dim3(256), 0, stream>>>(Xsb, S);
    k_topk  <<<dim3(10000),   dim3(256), 0, stream>>>(S, idxNS);
    k_refine<<<dim3(40000),   dim3(64),  0, stream>>>(Xs, idxNS, NS, valsd, idx10);
    k_dba   <<<dim3(40000),   dim3(128), 0, stream>>>(Xs, Q, valsd, idx10, out_x, out_rt, resd);
    k_sort  <<<dim3(100),     dim3(512), 0, stream>>>(resd, ranks, out_rr, out_pr);
  } else {
    int*    idx16 = (int*)   ((char*)d_ws + OOFF_IDX16);
    double* valsd = (double*)((char*)d_ws + OOFF_VALSD);
    int*    idx10 = (int*)   ((char*)d_ws + OOFF_IDX10);
    double* resd  = (double*)((char*)d_ws + OOFF_RESD);

    k_gather     <<<dim3(20000),   dim3(256), 0, stream>>>(X, ranks, Xs, (unsigned short*)0, 0);
    k_score_top16<<<dim3(13, 100), dim3(256), 0, stream>>>(Xs, idx16);
    k_refine     <<<dim3(40000),   dim3(64),  0, stream>>>(Xs, idx16, 16, valsd, idx10);
    k_dba        <<<dim3(40000),   dim3(128), 0, stream>>>(Xs, Q, valsd, idx10, out_x, out_rt, resd);
    k_sort       <<<dim3(100),     dim3(512), 0, stream>>>(resd, ranks, out_rr, out_pr);
  }
}